// Round 2
// baseline (54.264 us; speedup 1.0000x reference)
//
#include <hip/hip_runtime.h>
#include <hip/hip_bf16.h>
#include <hip/hip_fp16.h>

typedef unsigned int u32;
typedef unsigned short u16;
typedef short short8 __attribute__((ext_vector_type(8)));
typedef float f32x4 __attribute__((ext_vector_type(4)));

#define IN_F 4096
#define OUT_F 11008
#define MROWS 32
#define CCOLS 2048          // packed ints per output row (1 byte value per int)
#define NGRP 32
#define XB_OFF 64
#define XB_BYTES (MROWS * IN_F * 2)       // 262144
#define PART_OFF (XB_OFF + XB_BYTES)      // 262208 (16B aligned)
#define PBYTES ((size_t)MROWS * OUT_F * 4)

__device__ __forceinline__ float bf2f(u16 b) {
  u32 t = ((u32)b) << 16;
  return __builtin_bit_cast(float, t);
}
__device__ __forceinline__ u32 f2bf_rne(float f) {
  u32 b = __builtin_bit_cast(u32, f);
  return (b + 0x7FFFu + ((b >> 16) & 1u)) >> 16;
}
__device__ __forceinline__ float h2f(u16 h) {
  return __half2float(__builtin_bit_cast(__half, h));
}

// ---- mode detection: 0 = bf16 inputs, 1 = f32 inputs, 2 = f16 inputs ----
// scales values are in [0.001, 0.0211). Classify exponent-field of even u16s.
__global__ void qd_detect(const u16* __restrict__ sc, u32* __restrict__ flag) {
  int l = (int)threadIdx.x;                 // 0..63, one wave
  u16 u = sc[2 * l];
  int e = (u >> 7) & 0xFF;
  unsigned long long mA = __ballot(e >= 114 && e <= 124);  // bf16 exp of 0.001..0.021
  unsigned long long mC = __ballot(e >= 36 && e <= 88);    // f16 bit pattern range
  if (l == 0) {
    int cA = __popcll(mA), cC = __popcll(mC);
    flag[0] = (cA >= 48) ? 0u : ((cC >= 48) ? 2u : 1u);
  }
}

// ---- convert x to bf16 into ws ----
__global__ __launch_bounds__(256) void qd_xconv(const void* __restrict__ x,
                                                u16* __restrict__ xb,
                                                const u32* __restrict__ flag) {
  const u32 mode = flag[0];
  int t = (int)blockIdx.x * 256 + (int)threadIdx.x;   // 32768 threads
  int e = t * 4;
  if (e >= MROWS * IN_F) return;
  ushort4 r;
  if (mode == 1) {
    float4 v = *reinterpret_cast<const float4*>((const float*)x + e);
    r.x = (u16)f2bf_rne(v.x); r.y = (u16)f2bf_rne(v.y);
    r.z = (u16)f2bf_rne(v.z); r.w = (u16)f2bf_rne(v.w);
  } else if (mode == 2) {
    ushort4 h = *reinterpret_cast<const ushort4*>((const u16*)x + e);
    r.x = (u16)f2bf_rne(h2f(h.x)); r.y = (u16)f2bf_rne(h2f(h.y));
    r.z = (u16)f2bf_rne(h2f(h.z)); r.w = (u16)f2bf_rne(h2f(h.w));
  } else {
    r = *reinterpret_cast<const ushort4*>((const u16*)x + e);
  }
  *reinterpret_cast<ushort4*>(xb + e) = r;
}

__device__ __forceinline__ float ld_sz(const void* p, int idx, u32 mode) {
  if (mode == 0) return bf2f(((const u16*)p)[idx]);
  if (mode == 2) return h2f(((const u16*)p)[idx]);
  return ((const float*)p)[idx];
}

// dequant one packed int32 (one byte: high nibble = even k, low = odd k) -> 2 bf16
__device__ __forceinline__ u32 deq2(u32 v, float sf, float zadj) {
  // magic: 0x43000000 | (n<<16) == 128 + n exactly
  float uh = __builtin_bit_cast(float, 0x43000000u | ((v << 12) & 0xF0000u));
  float ul = __builtin_bit_cast(float, 0x43000000u | ((v << 16) & 0xF0000u));
  float wh = __builtin_fmaf(uh, sf, zadj);
  float wl = __builtin_fmaf(ul, sf, zadj);
  return f2bf_rne(wh) | (f2bf_rne(wl) << 16);
}

// ---- main: 16x16x32 bf16 MFMA, one wave = one 16-wide o-tile x one k-chunk ----
// A/B frag: lane q=lane&15 is the row/col, k = (lane>>4)*8 + j (contiguous).
// C/D: col = lane&15, row = (lane>>4)*4 + reg  [m89-verified].
template <int KS>
__global__ __launch_bounds__(256) void qd_main(
    const u16* __restrict__ xb, const int* __restrict__ packed,
    const void* __restrict__ scales, const void* __restrict__ zeros,
    float* __restrict__ part, const u32* __restrict__ flag) {
  const u32 mode = flag[0];
  const int lane = (int)(threadIdx.x & 63u);
  const int wid  = (int)(threadIdx.x >> 6u);
  const int tile = (int)blockIdx.x * 4 + wid;   // [0, 688)
  const int kc   = (int)blockIdx.y;             // [0, KS)
  const int q = lane & 15;
  const int p = lane >> 4;                      // 0..3
  const int o = tile * 16 + q;
  constexpr int STEPS = (IN_F / 32) / KS;       // k32-steps per wave
  const int s0 = kc * STEPS;

  f32x4 acc0 = {0.f, 0.f, 0.f, 0.f}, acc1 = {0.f, 0.f, 0.f, 0.f};
  const u16* xr0 = xb + q * IN_F + p * 8;
  const u16* xr1 = xr0 + 16 * IN_F;
  const int* pr = packed + (size_t)o * CCOLS + p * 4;

  for (int gg = 0; gg < STEPS / 4; ++gg) {      // 4 k32-steps per 128-k group
    const int g = kc * (STEPS / 4) + gg;
    const float sf = ld_sz(scales, o * NGRP + g, mode);
    const float zf = ld_sz(zeros, o * NGRP + g, mode);
    const float zadj = zf - 128.0f * sf;
#pragma unroll
    for (int s = 0; s < 4; ++s) {
      const int k32 = s0 + gg * 4 + s;
      const uint4 a0 = *reinterpret_cast<const uint4*>(xr0 + k32 * 32);
      const uint4 a1 = *reinterpret_cast<const uint4*>(xr1 + k32 * 32);
      const uint4 bv = *reinterpret_cast<const uint4*>(pr + k32 * 16);
      uint4 bw;
      bw.x = deq2(bv.x, sf, zadj);
      bw.y = deq2(bv.y, sf, zadj);
      bw.z = deq2(bv.z, sf, zadj);
      bw.w = deq2(bv.w, sf, zadj);
      const short8 af0 = __builtin_bit_cast(short8, a0);
      const short8 af1 = __builtin_bit_cast(short8, a1);
      const short8 bfr = __builtin_bit_cast(short8, bw);
      acc0 = __builtin_amdgcn_mfma_f32_16x16x32_bf16(af0, bfr, acc0, 0, 0, 0);
      acc1 = __builtin_amdgcn_mfma_f32_16x16x32_bf16(af1, bfr, acc1, 0, 0, 0);
    }
  }
  float* base = part + (size_t)kc * (MROWS * OUT_F);
#pragma unroll
  for (int r = 0; r < 4; ++r) {
    const int row = p * 4 + r;
    base[(size_t)row * OUT_F + o] = acc0[r];
    base[(size_t)(row + 16) * OUT_F + o] = acc1[r];
  }
}

template <int KS>
__global__ __launch_bounds__(256) void qd_reduce(
    const float* __restrict__ part, const void* __restrict__ bias,
    void* __restrict__ out, const u32* __restrict__ flag) {
  const u32 mode = flag[0];
  const int t = (int)blockIdx.x * 256 + (int)threadIdx.x;
  const int e = t * 4;
  if (e >= MROWS * OUT_F) return;
  const int o = e % OUT_F;   // e%4==0 and OUT_F%4==0 -> same row for all 4
  float4 s = {0.f, 0.f, 0.f, 0.f};
#pragma unroll
  for (int kc = 0; kc < KS; ++kc) {
    const float4 v = *reinterpret_cast<const float4*>(part + (size_t)kc * (MROWS * OUT_F) + e);
    s.x += v.x; s.y += v.y; s.z += v.z; s.w += v.w;
  }
  float b0, b1, b2, b3;
  if (mode == 0) {
    const ushort4 bb = *reinterpret_cast<const ushort4*>((const u16*)bias + o);
    b0 = bf2f(bb.x); b1 = bf2f(bb.y); b2 = bf2f(bb.z); b3 = bf2f(bb.w);
  } else if (mode == 2) {
    const ushort4 bb = *reinterpret_cast<const ushort4*>((const u16*)bias + o);
    b0 = h2f(bb.x); b1 = h2f(bb.y); b2 = h2f(bb.z); b3 = h2f(bb.w);
  } else {
    const float4 bb = *reinterpret_cast<const float4*>((const float*)bias + o);
    b0 = bb.x; b1 = bb.y; b2 = bb.z; b3 = bb.w;
  }
  s.x += b0; s.y += b1; s.z += b2; s.w += b3;
  if (mode == 0) {
    ushort4 r;
    r.x = (u16)f2bf_rne(s.x); r.y = (u16)f2bf_rne(s.y);
    r.z = (u16)f2bf_rne(s.z); r.w = (u16)f2bf_rne(s.w);
    *reinterpret_cast<ushort4*>((u16*)out + e) = r;
  } else {
    *reinterpret_cast<float4*>((float*)out + e) = s;
  }
}

// ---- fallback: single kernel, in-block LDS reduce, inline x conversion ----
__global__ __launch_bounds__(512) void qd_direct(
    const void* __restrict__ x, const int* __restrict__ packed,
    const void* __restrict__ scales, const void* __restrict__ zeros,
    const void* __restrict__ bias, void* __restrict__ out,
    const u32* __restrict__ flag, int forced) {
  const u32 mode = (forced >= 0) ? (u32)forced : flag[0];
  __shared__ float lds[8 * 512];
  const int lane = (int)(threadIdx.x & 63u);
  const int wid  = (int)(threadIdx.x >> 6u);   // kc in [0,8)
  const int tile = (int)blockIdx.x;            // [0,688)
  const int q = lane & 15;
  const int p = lane >> 4;
  const int o = tile * 16 + q;
  constexpr int STEPS = (IN_F / 32) / 8;       // 16
  const int s0 = wid * STEPS;

  f32x4 acc0 = {0.f,0.f,0.f,0.f}, acc1 = {0.f,0.f,0.f,0.f};
  const int* pr = packed + (size_t)o * CCOLS + p * 4;
  const int xoff0 = q * IN_F + p * 8;
  const int xoff1 = xoff0 + 16 * IN_F;

  for (int gg = 0; gg < STEPS / 4; ++gg) {
    const int g = wid * (STEPS / 4) + gg;
    const float sf = ld_sz(scales, o * NGRP + g, mode);
    const float zf = ld_sz(zeros, o * NGRP + g, mode);
    const float zadj = zf - 128.0f * sf;
#pragma unroll
    for (int s = 0; s < 4; ++s) {
      const int k32 = s0 + gg * 4 + s;
      uint4 a0, a1;
      if (mode == 1) {
        const float* xf = (const float*)x;
        float4 u0 = *reinterpret_cast<const float4*>(xf + xoff0 + k32 * 32);
        float4 u0b = *reinterpret_cast<const float4*>(xf + xoff0 + k32 * 32 + 4);
        float4 u1 = *reinterpret_cast<const float4*>(xf + xoff1 + k32 * 32);
        float4 u1b = *reinterpret_cast<const float4*>(xf + xoff1 + k32 * 32 + 4);
        a0.x = f2bf_rne(u0.x) | (f2bf_rne(u0.y) << 16);
        a0.y = f2bf_rne(u0.z) | (f2bf_rne(u0.w) << 16);
        a0.z = f2bf_rne(u0b.x) | (f2bf_rne(u0b.y) << 16);
        a0.w = f2bf_rne(u0b.z) | (f2bf_rne(u0b.w) << 16);
        a1.x = f2bf_rne(u1.x) | (f2bf_rne(u1.y) << 16);
        a1.y = f2bf_rne(u1.z) | (f2bf_rne(u1.w) << 16);
        a1.z = f2bf_rne(u1b.x) | (f2bf_rne(u1b.y) << 16);
        a1.w = f2bf_rne(u1b.z) | (f2bf_rne(u1b.w) << 16);
      } else if (mode == 2) {
        const u16* xh = (const u16*)x;
        uint4 h0 = *reinterpret_cast<const uint4*>(xh + xoff0 + k32 * 32);
        uint4 h1 = *reinterpret_cast<const uint4*>(xh + xoff1 + k32 * 32);
        u32 hv0[4] = {h0.x, h0.y, h0.z, h0.w}, hv1[4] = {h1.x, h1.y, h1.z, h1.w};
        u32 r0[4], r1[4];
#pragma unroll
        for (int j = 0; j < 4; ++j) {
          r0[j] = f2bf_rne(h2f((u16)(hv0[j] & 0xFFFF))) | (f2bf_rne(h2f((u16)(hv0[j] >> 16))) << 16);
          r1[j] = f2bf_rne(h2f((u16)(hv1[j] & 0xFFFF))) | (f2bf_rne(h2f((u16)(hv1[j] >> 16))) << 16);
        }
        a0 = {r0[0], r0[1], r0[2], r0[3]};
        a1 = {r1[0], r1[1], r1[2], r1[3]};
      } else {
        const u16* xu = (const u16*)x;
        a0 = *reinterpret_cast<const uint4*>(xu + xoff0 + k32 * 32);
        a1 = *reinterpret_cast<const uint4*>(xu + xoff1 + k32 * 32);
      }
      const uint4 bv = *reinterpret_cast<const uint4*>(pr + k32 * 16);
      uint4 bw;
      bw.x = deq2(bv.x, sf, zadj);
      bw.y = deq2(bv.y, sf, zadj);
      bw.z = deq2(bv.z, sf, zadj);
      bw.w = deq2(bv.w, sf, zadj);
      const short8 af0 = __builtin_bit_cast(short8, a0);
      const short8 af1 = __builtin_bit_cast(short8, a1);
      const short8 bfr = __builtin_bit_cast(short8, bw);
      acc0 = __builtin_amdgcn_mfma_f32_16x16x32_bf16(af0, bfr, acc0, 0, 0, 0);
      acc1 = __builtin_amdgcn_mfma_f32_16x16x32_bf16(af1, bfr, acc1, 0, 0, 0);
    }
  }
#pragma unroll
  for (int r = 0; r < 4; ++r) {
    lds[wid * 512 + (p * 4 + r) * 16 + q] = acc0[r];
    lds[wid * 512 + (p * 4 + r + 16) * 16 + q] = acc1[r];
  }
  __syncthreads();
  const int cell = (int)threadIdx.x;           // 512 cells = 32 rows x 16 cols
  const int row = cell >> 4, col = cell & 15;
  float ssum = 0.f;
#pragma unroll
  for (int w = 0; w < 8; ++w) ssum += lds[w * 512 + cell];
  const int oo = tile * 16 + col;
  ssum += ld_sz(bias, oo, mode);
  if (mode == 0) ((u16*)out)[(size_t)row * OUT_F + oo] = (u16)f2bf_rne(ssum);
  else ((float*)out)[(size_t)row * OUT_F + oo] = ssum;
}

extern "C" void kernel_launch(void* const* d_in, const int* in_sizes, int n_in,
                              void* d_out, int out_size, void* d_ws, size_t ws_size,
                              hipStream_t stream) {
  (void)in_sizes; (void)n_in; (void)out_size;
  const void* x      = d_in[0];
  const int* packed  = (const int*)d_in[1];
  const void* scales = d_in[2];
  const void* zeros  = d_in[3];
  const void* bias   = d_in[4];

  u32* flag = (u32*)d_ws;
  u16* xb = (u16*)((char*)d_ws + XB_OFF);
  float* part = (float*)((char*)d_ws + PART_OFF);

  if (ws_size >= PART_OFF + 4 * PBYTES) {
    qd_detect<<<1, 64, 0, stream>>>((const u16*)scales, flag);
    qd_xconv<<<128, 256, 0, stream>>>(x, xb, flag);
    qd_main<4><<<dim3(172, 4), 256, 0, stream>>>(xb, packed, scales, zeros, part, flag);
    qd_reduce<4><<<344, 256, 0, stream>>>(part, bias, d_out, flag);
  } else if (ws_size >= PART_OFF + 2 * PBYTES) {
    qd_detect<<<1, 64, 0, stream>>>((const u16*)scales, flag);
    qd_xconv<<<128, 256, 0, stream>>>(x, xb, flag);
    qd_main<2><<<dim3(172, 2), 256, 0, stream>>>(xb, packed, scales, zeros, part, flag);
    qd_reduce<2><<<344, 256, 0, stream>>>(part, bias, d_out, flag);
  } else if (ws_size >= 4) {
    qd_detect<<<1, 64, 0, stream>>>((const u16*)scales, flag);
    qd_direct<<<688, 512, 0, stream>>>(x, packed, scales, zeros, bias, d_out, flag, -1);
  } else {
    qd_direct<<<688, 512, 0, stream>>>(x, packed, scales, zeros, bias, d_out, (const u32*)nullptr, 1);
  }
}